// Round 5
// baseline (610.771 us; speedup 1.0000x reference)
//
#include <hip/hip_runtime.h>
#include <hip/hip_bf16.h>

#define N_NODES 50000
#define T_STEPS 8
#define CIN     32
#define HDIM    128
#define E_EDGES 800000
#define NBLK    196          // ceil(N_NODES/256)

typedef __attribute__((ext_vector_type(8))) short  short8;
typedef __attribute__((ext_vector_type(4))) float  f32x4;

__device__ __forceinline__ ushort f2b(float f) {
    __hip_bfloat16 b = __float2bfloat16(f);
    return *reinterpret_cast<ushort*>(&b);
}
__device__ __forceinline__ float b2f(ushort u) { return __uint_as_float(((uint)u) << 16); }
__device__ __forceinline__ float sigm(float x)  { return 1.f / (1.f + __expf(-x)); }
__device__ __forceinline__ float tanhx(float x) { float e = __expf(2.f * x); return 1.f - 2.f / (e + 1.f); }
// fragment-slot swizzle: spreads simultaneous epilogue writes across bank slots
__device__ __forceinline__ int SW(int fl) { return fl ^ (fl >> 3); }

// ---------------------------------------------------------------- CSR build
__global__ void k_deg(const int* __restrict__ ei, int* __restrict__ deg) {
    int e = blockIdx.x * 256 + threadIdx.x;
    if (e < E_EDGES) atomicAdd(&deg[ei[E_EDGES + e]], 1);
}

__global__ __launch_bounds__(256)
void k_scan1(const int* __restrict__ deg, int* __restrict__ incl, int* __restrict__ bsum) {
    __shared__ int sA[256], sB[256];
    int tid = threadIdx.x;
    int i = blockIdx.x * 256 + tid;
    sA[tid] = (i < N_NODES) ? deg[i] : 0;
    __syncthreads();
    int* rd = sA; int* wr = sB;
    for (int off = 1; off < 256; off <<= 1) {
        int v = rd[tid];
        if (tid >= off) v += rd[tid - off];
        wr[tid] = v;
        __syncthreads();
        int* tmp = rd; rd = wr; wr = tmp;
    }
    incl[i] = rd[tid];
    if (tid == 255) bsum[blockIdx.x] = rd[255];
}

__global__ void k_scan2(const int* __restrict__ bsum, int* __restrict__ boff,
                        int* __restrict__ row_ptr) {
    __shared__ int sA[256], sB[256];
    int tid = threadIdx.x;
    int v0 = (tid < NBLK) ? bsum[tid] : 0;
    sA[tid] = v0;
    __syncthreads();
    int* rd = sA; int* wr = sB;
    for (int off = 1; off < 256; off <<= 1) {
        int v = rd[tid];
        if (tid >= off) v += rd[tid - off];
        wr[tid] = v;
        __syncthreads();
        int* tmp = rd; rd = wr; wr = tmp;
    }
    if (tid < NBLK) boff[tid] = rd[tid] - v0;
    if (tid == NBLK - 1) row_ptr[N_NODES] = rd[tid];
}

__global__ __launch_bounds__(256)
void k_scan3(const int* __restrict__ deg, const int* __restrict__ incl,
             const int* __restrict__ boff, int* __restrict__ row_ptr,
             int* __restrict__ cursor, float* __restrict__ rdeg) {
    int i = blockIdx.x * 256 + threadIdx.x;
    if (i >= N_NODES) return;
    int d = deg[i];
    int excl = incl[i] - d + boff[blockIdx.x];
    row_ptr[i] = excl;
    cursor[i]  = excl;
    rdeg[i] = 1.0f / (float)max(d, 1);
}

__global__ void k_bucket(const int* __restrict__ ei, int* __restrict__ cursor,
                         int* __restrict__ csr_src) {
    int e = blockIdx.x * 256 + threadIdx.x;
    if (e < E_EDGES) {
        int d = ei[E_EDGES + e];
        int slot = atomicAdd(&cursor[d], 1);
        csr_src[slot] = ei[e];
    }
}

// ---------------------------------------------------------------- x -> bf16
__global__ __launch_bounds__(256)
void k_xbf(const float* __restrict__ x, ushort* __restrict__ xb) {
    size_t i = ((size_t)blockIdx.x * 256 + threadIdx.x) * 4;
    float4 v = *(const float4*)(x + i);
    ushort4 o; o.x = f2b(v.x); o.y = f2b(v.y); o.z = f2b(v.z); o.w = f2b(v.w);
    *(ushort4*)(xb + i) = o;
}

// ------------------------------------------------- fragment-order B packing
// Bf: rz [16 ct][8 ks][64][8] (cols 0-127 r, 128-255 z, K=256)
//     n1 @65536: [8 ct][4 ks][64][8] (n cols, sp half K=128, W_ih rows 256..383)
//     n2 @81920: [8 ct][4 ks][64][8] (n cols, h  half K=128, W_hh rows 256..383)
// Bsf: [8 ct][2 ks][64][8];  B2f: [6 ct][4 ks][64][8]
__global__ void k_pack(const float* __restrict__ Wih, const float* __restrict__ Whh,
                       const float* __restrict__ Wl,  const float* __restrict__ Wr,
                       const float* __restrict__ Wrec,const float* __restrict__ Wc1,
                       short* __restrict__ Bf, short* __restrict__ Bsf, short* __restrict__ B2f) {
    int i = blockIdx.x * 256 + threadIdx.x;
    if (i < 65536) {                                   // rz
        int b = i & 7, lane = (i >> 3) & 63, ks = (i >> 9) & 7, ct = i >> 12;
        int col = ct * 16 + (lane & 15);               // 0..255
        int k = ks * 32 + ((lane >> 4) << 3) + b;      // 0..255
        float v = (k < 128) ? Wih[col * 128 + k] : Whh[col * 128 + (k - 128)];
        Bf[i] = (short)f2b(v);
    } else if (i < 81920) {                            // n1
        int t2 = i - 65536;
        int b = t2 & 7, lane = (t2 >> 3) & 63, ks = (t2 >> 9) & 3, ct = t2 >> 11;
        int col = 256 + ct * 16 + (lane & 15);         // W_ih rows 256..383
        int k = ks * 32 + ((lane >> 4) << 3) + b;      // 0..127
        Bf[i] = (short)f2b(Wih[col * 128 + k]);
    } else if (i < 98304) {                            // n2
        int t2 = i - 81920;
        int b = t2 & 7, lane = (t2 >> 3) & 63, ks = (t2 >> 9) & 3, ct = t2 >> 11;
        int col = 256 + ct * 16 + (lane & 15);         // W_hh rows 256..383
        int k = ks * 32 + ((lane >> 4) << 3) + b;
        Bf[i] = (short)f2b(Whh[col * 128 + k]);
    } else if (i < 106496) {                           // Bsf
        int t2 = i - 98304;
        int b = t2 & 7, lane = (t2 >> 3) & 63, ks = (t2 >> 9) & 1, ct = t2 >> 10;
        int col = ct * 16 + (lane & 15);
        int k = ks * 32 + ((lane >> 4) << 3) + b;
        float v = (k < 32) ? Wl[col * 32 + k] : Wr[col * 32 + (k - 32)];
        Bsf[t2] = (short)f2b(v);
    } else if (i < 118784) {                           // B2f
        int t3 = i - 106496;
        int b = t3 & 7, lane = (t3 >> 3) & 63, ks = (t3 >> 9) & 3, ct = t3 >> 11;
        int col = ct * 16 + (lane & 15);
        int k = ks * 32 + ((lane >> 4) << 3) + b;
        float v = (col < 32) ? Wrec[col * 128 + k] : Wc1[(col - 32) * 128 + k];
        B2f[t3] = (short)f2b(v);
    }
}

// ---------------- mean aggregation over bf16 x, all timesteps, f32 accum
__global__ __launch_bounds__(256)
void k_agg_all(const ushort* __restrict__ xb, const int* __restrict__ row_ptr,
               const int* __restrict__ csr_src, const float* __restrict__ rdeg,
               ushort* __restrict__ aggb) {
    int g = blockIdx.x * 256 + threadIdx.x;
    int node = g >> 3, st = (g & 7) * 4;
    if (node >= N_NODES) return;
    int e0 = row_ptr[node], e1 = row_ptr[node + 1];
    float acc[8][4];
#pragma unroll
    for (int t = 0; t < 8; ++t)
#pragma unroll
        for (int c = 0; c < 4; ++c) acc[t][c] = 0.f;
    for (int e = e0; e < e1; ++e) {
        int s = csr_src[e];
        const ushort* b = xb + (size_t)s * (T_STEPS * CIN) + st;
#pragma unroll
        for (int t = 0; t < 8; ++t) {
            ushort4 v = *(const ushort4*)(b + t * CIN);
            acc[t][0] += b2f(v.x); acc[t][1] += b2f(v.y);
            acc[t][2] += b2f(v.z); acc[t][3] += b2f(v.w);
        }
    }
    float r = rdeg[node];
    ushort* o = aggb + (size_t)node * (T_STEPS * CIN) + st;
#pragma unroll
    for (int t = 0; t < 8; ++t) {
        ushort4 v; v.x = f2b(acc[t][0] * r); v.y = f2b(acc[t][1] * r);
        v.z = f2b(acc[t][2] * r); v.w = f2b(acc[t][3] * r);
        *(ushort4*)(o + t * CIN) = v;
    }
}

// --------- ALL 8 timesteps fused: SAGE + GRU + heads, 3 barriers/step
// block: 64 nodes x 512 threads (8 waves). wave wv owns 16-col slice j=wv*16+li.
// LDS shorts: A [8ks][4ri][64 slot][8] (32KB: ks0-3 sp, ks4-7 h);
//             A_s @16384 (8KB); c1f (f32) @20480 shorts (16KB). Total 56KB.
// Heads for step t computed in P1 of step t+1 (h(t) still staged); cls one later.
__global__ __launch_bounds__(512, 4)
void k_rec(const ushort* __restrict__ aggb, const ushort* __restrict__ xb,
           const short* __restrict__ Bsf, const short* __restrict__ Bf,
           const short* __restrict__ B2f,
           const float* __restrict__ bl,
           const float* __restrict__ b_ih, const float* __restrict__ b_hh,
           const float* __restrict__ b_rec, const float* __restrict__ b_c1,
           const float* __restrict__ W_c2, const float* __restrict__ b_c2,
           float* __restrict__ out_rec, float* __restrict__ out_cls) {
    __shared__ short lds[28672];
    float* c1f = (float*)&lds[20480];
    const int tid = threadIdx.x;
    const int nb  = blockIdx.x * 64;
    const int wv   = __builtin_amdgcn_readfirstlane(tid >> 6);
    const int lane = tid & 63;
    const int li   = lane & 15, lq = lane >> 4;
    const int j    = wv * 16 + li;

    // zero h region (A ks4..7)
    for (int c = tid; c < 1024; c += 512)
        *(short8*)&lds[8192 + c * 8] = (short8){0, 0, 0, 0, 0, 0, 0, 0};

    float hold[4][4];
#pragma unroll
    for (int ri = 0; ri < 4; ++ri)
#pragma unroll
        for (int q = 0; q < 4; ++q) hold[ri][q] = 0.f;

    // hoisted per-lane biases
    const float blc  = bl[j];
    const float br_  = b_ih[j]       + b_hh[j];
    const float bz_  = b_ih[128 + j] + b_hh[128 + j];
    const float bihn = b_ih[256 + j], bhhn = b_hh[256 + j];
    float bhead = 0.f;
    if (wv < 2)      bhead = b_rec[j];
    else if (wv < 6) bhead = b_c1[j - 32];

    // staging geometry + prefetch (t=0 in prologue)
    const int snode = tid >> 3, sk0 = (tid & 7) * 8;
    const int sgn = nb + snode;
    const ushort* sp0 = nullptr;
    if (sgn < N_NODES)
        sp0 = ((sk0 < 32) ? aggb : xb) + (size_t)sgn * (T_STEPS * CIN) + (sk0 & 31);
    const int sdst = 16384 + (((sk0 >> 5) * 4 + (snode >> 4)) * 64
                              + SW(((sk0 & 31) >> 3) * 16 + (snode & 15))) * 8;
    short8 pv = (short8){0, 0, 0, 0, 0, 0, 0, 0};
    if (sp0) pv = *(const short8*)(sp0);

    // heads GEMM on h currently staged in A ks4..7; writes out_rec(tt) / c1f
    auto do_heads = [&](int tt) {
        f32x4 accH[4];
#pragma unroll
        for (int ri = 0; ri < 4; ++ri) accH[ri] = (f32x4){0.f, 0.f, 0.f, 0.f};
#pragma unroll
        for (int ksh = 0; ksh < 4; ++ksh) {
            short8 a[4];
#pragma unroll
            for (int ri = 0; ri < 4; ++ri)
                a[ri] = *(short8*)&lds[(((4 + ksh) * 4 + ri) * 64 + SW(lane)) * 8];
            short8 b = *(const short8*)(B2f + ((wv * 4 + ksh) * 64 + lane) * 8);
#pragma unroll
            for (int ri = 0; ri < 4; ++ri)
                accH[ri] = __builtin_amdgcn_mfma_f32_16x16x32_bf16(a[ri], b, accH[ri], 0, 0, 0);
        }
        if (wv < 2) {
#pragma unroll
            for (int ri = 0; ri < 4; ++ri)
#pragma unroll
                for (int q = 0; q < 4; ++q) {
                    int row = ri * 16 + lq * 4 + q, gn = nb + row;
                    if (gn < N_NODES)
                        out_rec[(size_t)gn * (T_STEPS * 32) + tt * 32 + j] = accH[ri][q] + bhead;
                }
        } else {
            int cc = j - 32;
#pragma unroll
            for (int ri = 0; ri < 4; ++ri)
#pragma unroll
                for (int q = 0; q < 4; ++q) {
                    int row = ri * 16 + lq * 4 + q;
                    c1f[row * 64 + (cc ^ (row & 31))] = fmaxf(accH[ri][q] + bhead, 0.f);
                }
        }
    };
    auto do_cls = [&](int tt) {
        int node = tid >> 3, st = tid & 7, gn2 = nb + node;
        float s = 0.f;
#pragma unroll
        for (int c = 0; c < 8; ++c) {
            int q = st * 8 + c;
            s = fmaf(W_c2[q], c1f[node * 64 + (q ^ (node & 31))], s);
        }
        s += __shfl_xor(s, 1);
        s += __shfl_xor(s, 2);
        s += __shfl_xor(s, 4);
        if (st == 0 && gn2 < N_NODES)
            out_cls[(size_t)gn2 * T_STEPS + tt] = sigm(s + b_c2[0]);
    };

    for (int t = 0; t < T_STEPS; ++t) {
        // ---- stage A_s (prefetched regs) ----
        *(short8*)&lds[sdst] = pv;
        __syncthreads();                               // B1: A_s + h(t-1) ready
        if (sp0 && t + 1 < T_STEPS) pv = *(const short8*)(sp0 + (t + 1) * CIN);

        // ---- P1: SAGE(t) MFMA + heads(t-1) MFMA (disjoint LDS reads) ----
        {
            f32x4 accS[4];
#pragma unroll
            for (int ri = 0; ri < 4; ++ri) accS[ri] = (f32x4){0.f, 0.f, 0.f, 0.f};
#pragma unroll
            for (int ks = 0; ks < 2; ++ks) {
                short8 a[4];
#pragma unroll
                for (int ri = 0; ri < 4; ++ri)
                    a[ri] = *(short8*)&lds[16384 + ((ks * 4 + ri) * 64 + SW(lane)) * 8];
                short8 b = *(const short8*)(Bsf + ((wv * 2 + ks) * 64 + lane) * 8);
#pragma unroll
                for (int ri = 0; ri < 4; ++ri)
                    accS[ri] = __builtin_amdgcn_mfma_f32_16x16x32_bf16(a[ri], b, accS[ri], 0, 0, 0);
            }
            if (t > 0 && wv < 6) do_heads(t - 1);
            // write sp -> A ks0..3
            int ks_t = j >> 5, lh = (j & 31) >> 3, jj = j & 7;
#pragma unroll
            for (int ri = 0; ri < 4; ++ri)
#pragma unroll
                for (int q = 0; q < 4; ++q) {
                    float v = fmaxf(accS[ri][q] + blc, 0.f);
                    lds[((ks_t * 4 + ri) * 64 + SW(lh * 16 + lq * 4 + q)) * 8 + jj] = (short)f2b(v);
                }
        }
        __syncthreads();                               // B2: sp + c1f ready

        // ---- P2: GRU (rz K=256, n1/n2 K=128 sharing A-frags) ----
        f32x4 accRZ[2][4], accN1[4], accN2[4];
#pragma unroll
        for (int ri = 0; ri < 4; ++ri) {
            accRZ[0][ri] = (f32x4){0.f, 0.f, 0.f, 0.f};
            accRZ[1][ri] = (f32x4){0.f, 0.f, 0.f, 0.f};
            accN1[ri]    = (f32x4){0.f, 0.f, 0.f, 0.f};
            accN2[ri]    = (f32x4){0.f, 0.f, 0.f, 0.f};
        }
#pragma unroll
        for (int ks = 0; ks < 4; ++ks) {               // sp half
            short8 av[4];
#pragma unroll
            for (int ri = 0; ri < 4; ++ri)
                av[ri] = *(short8*)&lds[((ks * 4 + ri) * 64 + SW(lane)) * 8];
            short8 b0 = *(const short8*)(Bf + (((0 * 8 + wv) * 8 + ks) * 64 + lane) * 8);
            short8 b1 = *(const short8*)(Bf + (((1 * 8 + wv) * 8 + ks) * 64 + lane) * 8);
            short8 bn = *(const short8*)(Bf + (65536 + ((wv * 4 + ks) * 64 + lane) * 8));
#pragma unroll
            for (int ri = 0; ri < 4; ++ri) {
                accRZ[0][ri] = __builtin_amdgcn_mfma_f32_16x16x32_bf16(av[ri], b0, accRZ[0][ri], 0, 0, 0);
                accRZ[1][ri] = __builtin_amdgcn_mfma_f32_16x16x32_bf16(av[ri], b1, accRZ[1][ri], 0, 0, 0);
                accN1[ri]    = __builtin_amdgcn_mfma_f32_16x16x32_bf16(av[ri], bn, accN1[ri], 0, 0, 0);
            }
        }
#pragma unroll
        for (int ks = 4; ks < 8; ++ks) {               // h half
            short8 av[4];
#pragma unroll
            for (int ri = 0; ri < 4; ++ri)
                av[ri] = *(short8*)&lds[((ks * 4 + ri) * 64 + SW(lane)) * 8];
            short8 b0 = *(const short8*)(Bf + (((0 * 8 + wv) * 8 + ks) * 64 + lane) * 8);
            short8 b1 = *(const short8*)(Bf + (((1 * 8 + wv) * 8 + ks) * 64 + lane) * 8);
            short8 bn = *(const short8*)(Bf + (81920 + ((wv * 4 + (ks - 4)) * 64 + lane) * 8));
#pragma unroll
            for (int ri = 0; ri < 4; ++ri) {
                accRZ[0][ri] = __builtin_amdgcn_mfma_f32_16x16x32_bf16(av[ri], b0, accRZ[0][ri], 0, 0, 0);
                accRZ[1][ri] = __builtin_amdgcn_mfma_f32_16x16x32_bf16(av[ri], b1, accRZ[1][ri], 0, 0, 0);
                accN2[ri]    = __builtin_amdgcn_mfma_f32_16x16x32_bf16(av[ri], bn, accN2[ri], 0, 0, 0);
            }
        }

        // ---- gates: h fp32 in registers across steps ----
#pragma unroll
        for (int ri = 0; ri < 4; ++ri)
#pragma unroll
            for (int q = 0; q < 4; ++q) {
                float r = sigm(accRZ[0][ri][q] + br_);
                float z = sigm(accRZ[1][ri][q] + bz_);
                float nn = tanhx(accN1[ri][q] + bihn + r * (accN2[ri][q] + bhhn));
                hold[ri][q] = (1.f - z) * nn + z * hold[ri][q];
            }
        if (t > 0) do_cls(t - 1);
        __syncthreads();                               // B3: all A-reads done

        // ---- h(t) -> A ks4..7 ----
        {
            int ks_h = 4 + (j >> 5), lh_h = (j & 31) >> 3, jj_h = j & 7;
#pragma unroll
            for (int ri = 0; ri < 4; ++ri)
#pragma unroll
                for (int q = 0; q < 4; ++q)
                    lds[((ks_h * 4 + ri) * 64 + SW(lh_h * 16 + lq * 4 + q)) * 8 + jj_h]
                        = (short)f2b(hold[ri][q]);
        }
    }

    // ---- epilogue: heads + cls for t = 7 ----
    __syncthreads();
    if (wv < 6) do_heads(T_STEPS - 1);
    __syncthreads();
    do_cls(T_STEPS - 1);
}

// ---------------------------------------------------------------- launcher
extern "C" void kernel_launch(void* const* d_in, const int* in_sizes, int n_in,
                              void* d_out, int out_size, void* d_ws, size_t ws_size,
                              hipStream_t stream) {
    const float* x     = (const float*)d_in[0];
    const int*   ei    = (const int*)  d_in[1];
    const float* Wl    = (const float*)d_in[2];
    const float* bl    = (const float*)d_in[3];
    const float* Wr    = (const float*)d_in[4];
    const float* W_ih  = (const float*)d_in[5];
    const float* b_ih  = (const float*)d_in[6];
    const float* W_hh  = (const float*)d_in[7];
    const float* b_hh  = (const float*)d_in[8];
    const float* W_rec = (const float*)d_in[9];
    const float* b_rec = (const float*)d_in[10];
    const float* W_c1  = (const float*)d_in[11];
    const float* b_c1  = (const float*)d_in[12];
    const float* W_c2  = (const float*)d_in[13];
    const float* b_c2  = (const float*)d_in[14];

    char* wp = (char*)d_ws;
    auto alloc = [&](size_t bytes) -> char* {
        char* p = wp; wp += (bytes + 255) & ~(size_t)255; return p;
    };
    int*    deg     = (int*)   alloc((size_t)N_NODES * 4);
    int*    row_ptr = (int*)   alloc((size_t)(N_NODES + 1) * 4);
    int*    cursor  = (int*)   alloc((size_t)N_NODES * 4);
    int*    csr_src = (int*)   alloc((size_t)E_EDGES * 4);
    float*  rdeg    = (float*) alloc((size_t)N_NODES * 4);
    int*    incl    = (int*)   alloc((size_t)NBLK * 256 * 4);
    int*    bsum    = (int*)   alloc((size_t)256 * 4);
    int*    boff    = (int*)   alloc((size_t)256 * 4);
    short*  Bf      = (short*) alloc((size_t)98304 * 2);
    short*  Bsf     = (short*) alloc((size_t)8192 * 2);
    short*  B2f     = (short*) alloc((size_t)12288 * 2);
    ushort* xb      = (ushort*)alloc((size_t)N_NODES * T_STEPS * CIN * 2);
    ushort* aggb    = (ushort*)alloc((size_t)N_NODES * T_STEPS * CIN * 2);

    float* out_rec = (float*)d_out;
    float* out_cls = out_rec + (size_t)N_NODES * T_STEPS * 32;

    hipMemsetAsync(deg, 0, (size_t)N_NODES * 4, stream);

    k_deg   <<<(E_EDGES + 255) / 256, 256, 0, stream>>>(ei, deg);
    k_scan1 <<<NBLK, 256, 0, stream>>>(deg, incl, bsum);
    k_scan2 <<<1, 256, 0, stream>>>(bsum, boff, row_ptr);
    k_scan3 <<<NBLK, 256, 0, stream>>>(deg, incl, boff, row_ptr, cursor, rdeg);
    k_bucket<<<(E_EDGES + 255) / 256, 256, 0, stream>>>(ei, cursor, csr_src);
    k_xbf   <<<12500, 256, 0, stream>>>(x, xb);
    k_pack  <<<464, 256, 0, stream>>>(W_ih, W_hh, Wl, Wr, W_rec, W_c1, Bf, Bsf, B2f);

    k_agg_all<<<(N_NODES * 8 + 255) / 256, 256, 0, stream>>>(
        xb, row_ptr, csr_src, rdeg, aggb);
    k_rec<<<(N_NODES + 63) / 64, 512, 0, stream>>>(
        aggb, xb, Bsf, Bf, B2f, bl, b_ih, b_hh, b_rec, b_c1, W_c2, b_c2,
        out_rec, out_cls);
}

// Round 6
// 465.025 us; speedup vs baseline: 1.3134x; 1.3134x over previous
//
#include <hip/hip_runtime.h>
#include <hip/hip_bf16.h>

#define N_NODES 50000
#define T_STEPS 8
#define CIN     32
#define HDIM    128
#define E_EDGES 800000
#define NBLK    196          // ceil(N_NODES/256)

typedef __attribute__((ext_vector_type(8))) short  short8;
typedef __attribute__((ext_vector_type(4))) float  f32x4;

__device__ __forceinline__ ushort f2b(float f) {
    __hip_bfloat16 b = __float2bfloat16(f);
    return *reinterpret_cast<ushort*>(&b);
}
__device__ __forceinline__ float b2f(ushort u) { return __uint_as_float(((uint)u) << 16); }
__device__ __forceinline__ float sigm(float x)  { return 1.f / (1.f + __expf(-x)); }
__device__ __forceinline__ float tanhx(float x) { float e = __expf(2.f * x); return 1.f - 2.f / (e + 1.f); }
// fragment-slot swizzle: spreads simultaneous epilogue writes across bank slots
__device__ __forceinline__ int SW(int fl) { return fl ^ (fl >> 3); }

// ---------------------------------------------------------------- CSR build
__global__ void k_deg(const int* __restrict__ ei, int* __restrict__ deg) {
    int e = blockIdx.x * 256 + threadIdx.x;
    if (e < E_EDGES) atomicAdd(&deg[ei[E_EDGES + e]], 1);
}

__global__ __launch_bounds__(256)
void k_scan1(const int* __restrict__ deg, int* __restrict__ incl, int* __restrict__ bsum) {
    __shared__ int sA[256], sB[256];
    int tid = threadIdx.x;
    int i = blockIdx.x * 256 + tid;
    sA[tid] = (i < N_NODES) ? deg[i] : 0;
    __syncthreads();
    int* rd = sA; int* wr = sB;
    for (int off = 1; off < 256; off <<= 1) {
        int v = rd[tid];
        if (tid >= off) v += rd[tid - off];
        wr[tid] = v;
        __syncthreads();
        int* tmp = rd; rd = wr; wr = tmp;
    }
    incl[i] = rd[tid];
    if (tid == 255) bsum[blockIdx.x] = rd[255];
}

__global__ void k_scan2(const int* __restrict__ bsum, int* __restrict__ boff,
                        int* __restrict__ row_ptr) {
    __shared__ int sA[256], sB[256];
    int tid = threadIdx.x;
    int v0 = (tid < NBLK) ? bsum[tid] : 0;
    sA[tid] = v0;
    __syncthreads();
    int* rd = sA; int* wr = sB;
    for (int off = 1; off < 256; off <<= 1) {
        int v = rd[tid];
        if (tid >= off) v += rd[tid - off];
        wr[tid] = v;
        __syncthreads();
        int* tmp = rd; rd = wr; wr = tmp;
    }
    if (tid < NBLK) boff[tid] = rd[tid] - v0;
    if (tid == NBLK - 1) row_ptr[N_NODES] = rd[tid];
}

__global__ __launch_bounds__(256)
void k_scan3(const int* __restrict__ deg, const int* __restrict__ incl,
             const int* __restrict__ boff, int* __restrict__ row_ptr,
             int* __restrict__ cursor, float* __restrict__ rdeg) {
    int i = blockIdx.x * 256 + threadIdx.x;
    if (i >= N_NODES) return;
    int d = deg[i];
    int excl = incl[i] - d + boff[blockIdx.x];
    row_ptr[i] = excl;
    cursor[i]  = excl;
    rdeg[i] = 1.0f / (float)max(d, 1);
}

__global__ void k_bucket(const int* __restrict__ ei, int* __restrict__ cursor,
                         int* __restrict__ csr_src) {
    int e = blockIdx.x * 256 + threadIdx.x;
    if (e < E_EDGES) {
        int d = ei[E_EDGES + e];
        int slot = atomicAdd(&cursor[d], 1);
        csr_src[slot] = ei[e];
    }
}

// ---------------------------------------------------------------- x -> bf16
__global__ __launch_bounds__(256)
void k_xbf(const float* __restrict__ x, ushort* __restrict__ xb) {
    size_t i = ((size_t)blockIdx.x * 256 + threadIdx.x) * 4;
    float4 v = *(const float4*)(x + i);
    ushort4 o; o.x = f2b(v.x); o.y = f2b(v.y); o.z = f2b(v.z); o.w = f2b(v.w);
    *(ushort4*)(xb + i) = o;
}

// ------------------------------------------------- fragment-order B packing
// Bf: rz [16 ct][8 ks][64][8] (cols 0-127 r, 128-255 z, K=256)
//     n1 @65536: [8 ct][4 ks][64][8] (n cols, sp half K=128, W_ih rows 256..383)
//     n2 @81920: [8 ct][4 ks][64][8] (n cols, h  half K=128, W_hh rows 256..383)
// Bsf: [8 ct][2 ks][64][8];  B2f: [6 ct][4 ks][64][8]
__global__ void k_pack(const float* __restrict__ Wih, const float* __restrict__ Whh,
                       const float* __restrict__ Wl,  const float* __restrict__ Wr,
                       const float* __restrict__ Wrec,const float* __restrict__ Wc1,
                       short* __restrict__ Bf, short* __restrict__ Bsf, short* __restrict__ B2f) {
    int i = blockIdx.x * 256 + threadIdx.x;
    if (i < 65536) {                                   // rz
        int b = i & 7, lane = (i >> 3) & 63, ks = (i >> 9) & 7, ct = i >> 12;
        int col = ct * 16 + (lane & 15);               // 0..255
        int k = ks * 32 + ((lane >> 4) << 3) + b;      // 0..255
        float v = (k < 128) ? Wih[col * 128 + k] : Whh[col * 128 + (k - 128)];
        Bf[i] = (short)f2b(v);
    } else if (i < 81920) {                            // n1
        int t2 = i - 65536;
        int b = t2 & 7, lane = (t2 >> 3) & 63, ks = (t2 >> 9) & 3, ct = t2 >> 11;
        int col = 256 + ct * 16 + (lane & 15);         // W_ih rows 256..383
        int k = ks * 32 + ((lane >> 4) << 3) + b;      // 0..127
        Bf[i] = (short)f2b(Wih[col * 128 + k]);
    } else if (i < 98304) {                            // n2
        int t2 = i - 81920;
        int b = t2 & 7, lane = (t2 >> 3) & 63, ks = (t2 >> 9) & 3, ct = t2 >> 11;
        int col = 256 + ct * 16 + (lane & 15);         // W_hh rows 256..383
        int k = ks * 32 + ((lane >> 4) << 3) + b;
        Bf[i] = (short)f2b(Whh[col * 128 + k]);
    } else if (i < 106496) {                           // Bsf
        int t2 = i - 98304;
        int b = t2 & 7, lane = (t2 >> 3) & 63, ks = (t2 >> 9) & 1, ct = t2 >> 10;
        int col = ct * 16 + (lane & 15);
        int k = ks * 32 + ((lane >> 4) << 3) + b;
        float v = (k < 32) ? Wl[col * 32 + k] : Wr[col * 32 + (k - 32)];
        Bsf[t2] = (short)f2b(v);
    } else if (i < 118784) {                           // B2f
        int t3 = i - 106496;
        int b = t3 & 7, lane = (t3 >> 3) & 63, ks = (t3 >> 9) & 3, ct = t3 >> 11;
        int col = ct * 16 + (lane & 15);
        int k = ks * 32 + ((lane >> 4) << 3) + b;
        float v = (col < 32) ? Wrec[col * 128 + k] : Wc1[(col - 32) * 128 + k];
        B2f[t3] = (short)f2b(v);
    }
}

// ---------------- mean aggregation over bf16 x, all timesteps, f32 accum
__global__ __launch_bounds__(256)
void k_agg_all(const ushort* __restrict__ xb, const int* __restrict__ row_ptr,
               const int* __restrict__ csr_src, const float* __restrict__ rdeg,
               ushort* __restrict__ aggb) {
    int g = blockIdx.x * 256 + threadIdx.x;
    int node = g >> 3, st = (g & 7) * 4;
    if (node >= N_NODES) return;
    int e0 = row_ptr[node], e1 = row_ptr[node + 1];
    float acc[8][4];
#pragma unroll
    for (int t = 0; t < 8; ++t)
#pragma unroll
        for (int c = 0; c < 4; ++c) acc[t][c] = 0.f;
    for (int e = e0; e < e1; ++e) {
        int s = csr_src[e];
        const ushort* b = xb + (size_t)s * (T_STEPS * CIN) + st;
#pragma unroll
        for (int t = 0; t < 8; ++t) {
            ushort4 v = *(const ushort4*)(b + t * CIN);
            acc[t][0] += b2f(v.x); acc[t][1] += b2f(v.y);
            acc[t][2] += b2f(v.z); acc[t][3] += b2f(v.w);
        }
    }
    float r = rdeg[node];
    ushort* o = aggb + (size_t)node * (T_STEPS * CIN) + st;
#pragma unroll
    for (int t = 0; t < 8; ++t) {
        ushort4 v; v.x = f2b(acc[t][0] * r); v.y = f2b(acc[t][1] * r);
        v.z = f2b(acc[t][2] * r); v.w = f2b(acc[t][3] * r);
        *(ushort4*)(o + t * CIN) = v;
    }
}

// --------- ALL 8 timesteps fused: SAGE + GRU + heads, 3 barriers/step
// block: 64 nodes x 512 threads (8 waves). wave wv owns 16-col slice j=wv*16+li.
// LDS shorts: A [8ks][4ri][64 slot][8] (32KB: ks0-3 sp, ks4-7 h);
//             A_s @16384 (8KB); c1f (f32) @20480 shorts (16KB). Total 56KB.
// Heads for step t computed in P1 of step t+1 (h(t) still staged); cls one later.
// NOTE: (512,2) not (512,4) — LDS already caps at 2 blocks/CU; tighter bound
// spills MFMA accumulators to scratch (R5: 387MB WRITE_SIZE, 474us).
__global__ __launch_bounds__(512, 2)
void k_rec(const ushort* __restrict__ aggb, const ushort* __restrict__ xb,
           const short* __restrict__ Bsf, const short* __restrict__ Bf,
           const short* __restrict__ B2f,
           const float* __restrict__ bl,
           const float* __restrict__ b_ih, const float* __restrict__ b_hh,
           const float* __restrict__ b_rec, const float* __restrict__ b_c1,
           const float* __restrict__ W_c2, const float* __restrict__ b_c2,
           float* __restrict__ out_rec, float* __restrict__ out_cls) {
    __shared__ short lds[28672];
    float* c1f = (float*)&lds[20480];
    const int tid = threadIdx.x;
    const int nb  = blockIdx.x * 64;
    const int wv   = __builtin_amdgcn_readfirstlane(tid >> 6);
    const int lane = tid & 63;
    const int li   = lane & 15, lq = lane >> 4;
    const int j    = wv * 16 + li;

    // zero h region (A ks4..7)
    for (int c = tid; c < 1024; c += 512)
        *(short8*)&lds[8192 + c * 8] = (short8){0, 0, 0, 0, 0, 0, 0, 0};

    float hold[4][4];
#pragma unroll
    for (int ri = 0; ri < 4; ++ri)
#pragma unroll
        for (int q = 0; q < 4; ++q) hold[ri][q] = 0.f;

    // hoisted per-lane biases
    const float blc  = bl[j];
    const float br_  = b_ih[j]       + b_hh[j];
    const float bz_  = b_ih[128 + j] + b_hh[128 + j];
    const float bihn = b_ih[256 + j], bhhn = b_hh[256 + j];
    float bhead = 0.f;
    if (wv < 2)      bhead = b_rec[j];
    else if (wv < 6) bhead = b_c1[j - 32];

    // staging geometry + prefetch (t=0 in prologue)
    const int snode = tid >> 3, sk0 = (tid & 7) * 8;
    const int sgn = nb + snode;
    const ushort* sp0 = nullptr;
    if (sgn < N_NODES)
        sp0 = ((sk0 < 32) ? aggb : xb) + (size_t)sgn * (T_STEPS * CIN) + (sk0 & 31);
    const int sdst = 16384 + (((sk0 >> 5) * 4 + (snode >> 4)) * 64
                              + SW(((sk0 & 31) >> 3) * 16 + (snode & 15))) * 8;
    short8 pv = (short8){0, 0, 0, 0, 0, 0, 0, 0};
    if (sp0) pv = *(const short8*)(sp0);

    // heads GEMM on h currently staged in A ks4..7; writes out_rec(tt) / c1f
    auto do_heads = [&](int tt) {
        f32x4 accH[4];
#pragma unroll
        for (int ri = 0; ri < 4; ++ri) accH[ri] = (f32x4){0.f, 0.f, 0.f, 0.f};
#pragma unroll
        for (int ksh = 0; ksh < 4; ++ksh) {
            short8 a[4];
#pragma unroll
            for (int ri = 0; ri < 4; ++ri)
                a[ri] = *(short8*)&lds[(((4 + ksh) * 4 + ri) * 64 + SW(lane)) * 8];
            short8 b = *(const short8*)(B2f + ((wv * 4 + ksh) * 64 + lane) * 8);
#pragma unroll
            for (int ri = 0; ri < 4; ++ri)
                accH[ri] = __builtin_amdgcn_mfma_f32_16x16x32_bf16(a[ri], b, accH[ri], 0, 0, 0);
        }
        if (wv < 2) {
#pragma unroll
            for (int ri = 0; ri < 4; ++ri)
#pragma unroll
                for (int q = 0; q < 4; ++q) {
                    int row = ri * 16 + lq * 4 + q, gn = nb + row;
                    if (gn < N_NODES)
                        out_rec[(size_t)gn * (T_STEPS * 32) + tt * 32 + j] = accH[ri][q] + bhead;
                }
        } else {
            int cc = j - 32;
#pragma unroll
            for (int ri = 0; ri < 4; ++ri)
#pragma unroll
                for (int q = 0; q < 4; ++q) {
                    int row = ri * 16 + lq * 4 + q;
                    c1f[row * 64 + (cc ^ (row & 31))] = fmaxf(accH[ri][q] + bhead, 0.f);
                }
        }
    };
    auto do_cls = [&](int tt) {
        int node = tid >> 3, st = tid & 7, gn2 = nb + node;
        float s = 0.f;
#pragma unroll
        for (int c = 0; c < 8; ++c) {
            int q = st * 8 + c;
            s = fmaf(W_c2[q], c1f[node * 64 + (q ^ (node & 31))], s);
        }
        s += __shfl_xor(s, 1);
        s += __shfl_xor(s, 2);
        s += __shfl_xor(s, 4);
        if (st == 0 && gn2 < N_NODES)
            out_cls[(size_t)gn2 * T_STEPS + tt] = sigm(s + b_c2[0]);
    };

    for (int t = 0; t < T_STEPS; ++t) {
        // ---- stage A_s (prefetched regs) ----
        *(short8*)&lds[sdst] = pv;
        __syncthreads();                               // B1: A_s + h(t-1) ready
        if (sp0 && t + 1 < T_STEPS) pv = *(const short8*)(sp0 + (t + 1) * CIN);

        // ---- P1: SAGE(t) MFMA + heads(t-1) MFMA (disjoint LDS reads) ----
        {
            f32x4 accS[4];
#pragma unroll
            for (int ri = 0; ri < 4; ++ri) accS[ri] = (f32x4){0.f, 0.f, 0.f, 0.f};
#pragma unroll
            for (int ks = 0; ks < 2; ++ks) {
                short8 a[4];
#pragma unroll
                for (int ri = 0; ri < 4; ++ri)
                    a[ri] = *(short8*)&lds[16384 + ((ks * 4 + ri) * 64 + SW(lane)) * 8];
                short8 b = *(const short8*)(Bsf + ((wv * 2 + ks) * 64 + lane) * 8);
#pragma unroll
                for (int ri = 0; ri < 4; ++ri)
                    accS[ri] = __builtin_amdgcn_mfma_f32_16x16x32_bf16(a[ri], b, accS[ri], 0, 0, 0);
            }
            if (t > 0 && wv < 6) do_heads(t - 1);
            // write sp -> A ks0..3
            int ks_t = j >> 5, lh = (j & 31) >> 3, jj = j & 7;
#pragma unroll
            for (int ri = 0; ri < 4; ++ri)
#pragma unroll
                for (int q = 0; q < 4; ++q) {
                    float v = fmaxf(accS[ri][q] + blc, 0.f);
                    lds[((ks_t * 4 + ri) * 64 + SW(lh * 16 + lq * 4 + q)) * 8 + jj] = (short)f2b(v);
                }
        }
        __syncthreads();                               // B2: sp + c1f ready

        // ---- P2: GRU (rz K=256, n1/n2 K=128 sharing A-frags) ----
        f32x4 accRZ[2][4], accN1[4], accN2[4];
#pragma unroll
        for (int ri = 0; ri < 4; ++ri) {
            accRZ[0][ri] = (f32x4){0.f, 0.f, 0.f, 0.f};
            accRZ[1][ri] = (f32x4){0.f, 0.f, 0.f, 0.f};
            accN1[ri]    = (f32x4){0.f, 0.f, 0.f, 0.f};
            accN2[ri]    = (f32x4){0.f, 0.f, 0.f, 0.f};
        }
#pragma unroll
        for (int ks = 0; ks < 4; ++ks) {               // sp half
            short8 av[4];
#pragma unroll
            for (int ri = 0; ri < 4; ++ri)
                av[ri] = *(short8*)&lds[((ks * 4 + ri) * 64 + SW(lane)) * 8];
            short8 b0 = *(const short8*)(Bf + (((0 * 8 + wv) * 8 + ks) * 64 + lane) * 8);
            short8 b1 = *(const short8*)(Bf + (((1 * 8 + wv) * 8 + ks) * 64 + lane) * 8);
            short8 bn = *(const short8*)(Bf + (65536 + ((wv * 4 + ks) * 64 + lane) * 8));
#pragma unroll
            for (int ri = 0; ri < 4; ++ri) {
                accRZ[0][ri] = __builtin_amdgcn_mfma_f32_16x16x32_bf16(av[ri], b0, accRZ[0][ri], 0, 0, 0);
                accRZ[1][ri] = __builtin_amdgcn_mfma_f32_16x16x32_bf16(av[ri], b1, accRZ[1][ri], 0, 0, 0);
                accN1[ri]    = __builtin_amdgcn_mfma_f32_16x16x32_bf16(av[ri], bn, accN1[ri], 0, 0, 0);
            }
        }
#pragma unroll
        for (int ks = 4; ks < 8; ++ks) {               // h half
            short8 av[4];
#pragma unroll
            for (int ri = 0; ri < 4; ++ri)
                av[ri] = *(short8*)&lds[((ks * 4 + ri) * 64 + SW(lane)) * 8];
            short8 b0 = *(const short8*)(Bf + (((0 * 8 + wv) * 8 + ks) * 64 + lane) * 8);
            short8 b1 = *(const short8*)(Bf + (((1 * 8 + wv) * 8 + ks) * 64 + lane) * 8);
            short8 bn = *(const short8*)(Bf + (81920 + ((wv * 4 + (ks - 4)) * 64 + lane) * 8));
#pragma unroll
            for (int ri = 0; ri < 4; ++ri) {
                accRZ[0][ri] = __builtin_amdgcn_mfma_f32_16x16x32_bf16(av[ri], b0, accRZ[0][ri], 0, 0, 0);
                accRZ[1][ri] = __builtin_amdgcn_mfma_f32_16x16x32_bf16(av[ri], b1, accRZ[1][ri], 0, 0, 0);
                accN2[ri]    = __builtin_amdgcn_mfma_f32_16x16x32_bf16(av[ri], bn, accN2[ri], 0, 0, 0);
            }
        }

        // ---- gates: h fp32 in registers across steps ----
#pragma unroll
        for (int ri = 0; ri < 4; ++ri)
#pragma unroll
            for (int q = 0; q < 4; ++q) {
                float r = sigm(accRZ[0][ri][q] + br_);
                float z = sigm(accRZ[1][ri][q] + bz_);
                float nn = tanhx(accN1[ri][q] + bihn + r * (accN2[ri][q] + bhhn));
                hold[ri][q] = (1.f - z) * nn + z * hold[ri][q];
            }
        if (t > 0) do_cls(t - 1);
        __syncthreads();                               // B3: all A-reads done

        // ---- h(t) -> A ks4..7 ----
        {
            int ks_h = 4 + (j >> 5), lh_h = (j & 31) >> 3, jj_h = j & 7;
#pragma unroll
            for (int ri = 0; ri < 4; ++ri)
#pragma unroll
                for (int q = 0; q < 4; ++q)
                    lds[((ks_h * 4 + ri) * 64 + SW(lh_h * 16 + lq * 4 + q)) * 8 + jj_h]
                        = (short)f2b(hold[ri][q]);
        }
    }

    // ---- epilogue: heads + cls for t = 7 ----
    __syncthreads();
    if (wv < 6) do_heads(T_STEPS - 1);
    __syncthreads();
    do_cls(T_STEPS - 1);
}

// ---------------------------------------------------------------- launcher
extern "C" void kernel_launch(void* const* d_in, const int* in_sizes, int n_in,
                              void* d_out, int out_size, void* d_ws, size_t ws_size,
                              hipStream_t stream) {
    const float* x     = (const float*)d_in[0];
    const int*   ei    = (const int*)  d_in[1];
    const float* Wl    = (const float*)d_in[2];
    const float* bl    = (const float*)d_in[3];
    const float* Wr    = (const float*)d_in[4];
    const float* W_ih  = (const float*)d_in[5];
    const float* b_ih  = (const float*)d_in[6];
    const float* W_hh  = (const float*)d_in[7];
    const float* b_hh  = (const float*)d_in[8];
    const float* W_rec = (const float*)d_in[9];
    const float* b_rec = (const float*)d_in[10];
    const float* W_c1  = (const float*)d_in[11];
    const float* b_c1  = (const float*)d_in[12];
    const float* W_c2  = (const float*)d_in[13];
    const float* b_c2  = (const float*)d_in[14];

    char* wp = (char*)d_ws;
    auto alloc = [&](size_t bytes) -> char* {
        char* p = wp; wp += (bytes + 255) & ~(size_t)255; return p;
    };
    int*    deg     = (int*)   alloc((size_t)N_NODES * 4);
    int*    row_ptr = (int*)   alloc((size_t)(N_NODES + 1) * 4);
    int*    cursor  = (int*)   alloc((size_t)N_NODES * 4);
    int*    csr_src = (int*)   alloc((size_t)E_EDGES * 4);
    float*  rdeg    = (float*) alloc((size_t)N_NODES * 4);
    int*    incl    = (int*)   alloc((size_t)NBLK * 256 * 4);
    int*    bsum    = (int*)   alloc((size_t)256 * 4);
    int*    boff    = (int*)   alloc((size_t)256 * 4);
    short*  Bf      = (short*) alloc((size_t)98304 * 2);
    short*  Bsf     = (short*) alloc((size_t)8192 * 2);
    short*  B2f     = (short*) alloc((size_t)12288 * 2);
    ushort* xb      = (ushort*)alloc((size_t)N_NODES * T_STEPS * CIN * 2);
    ushort* aggb    = (ushort*)alloc((size_t)N_NODES * T_STEPS * CIN * 2);

    float* out_rec = (float*)d_out;
    float* out_cls = out_rec + (size_t)N_NODES * T_STEPS * 32;

    hipMemsetAsync(deg, 0, (size_t)N_NODES * 4, stream);

    k_deg   <<<(E_EDGES + 255) / 256, 256, 0, stream>>>(ei, deg);
    k_scan1 <<<NBLK, 256, 0, stream>>>(deg, incl, bsum);
    k_scan2 <<<1, 256, 0, stream>>>(bsum, boff, row_ptr);
    k_scan3 <<<NBLK, 256, 0, stream>>>(deg, incl, boff, row_ptr, cursor, rdeg);
    k_bucket<<<(E_EDGES + 255) / 256, 256, 0, stream>>>(ei, cursor, csr_src);
    k_xbf   <<<12500, 256, 0, stream>>>(x, xb);
    k_pack  <<<464, 256, 0, stream>>>(W_ih, W_hh, Wl, Wr, W_rec, W_c1, Bf, Bsf, B2f);

    k_agg_all<<<(N_NODES * 8 + 255) / 256, 256, 0, stream>>>(
        xb, row_ptr, csr_src, rdeg, aggb);
    k_rec<<<(N_NODES + 63) / 64, 512, 0, stream>>>(
        aggb, xb, Bsf, Bf, B2f, bl, b_ih, b_hh, b_rec, b_c1, W_c2, b_c2,
        out_rec, out_cls);
}

// Round 7
// 446.368 us; speedup vs baseline: 1.3683x; 1.0418x over previous
//
#include <hip/hip_runtime.h>
#include <hip/hip_bf16.h>

#define N_NODES 50000
#define T_STEPS 8
#define CIN     32
#define HDIM    128
#define E_EDGES 800000
#define NBLK    196          // ceil(N_NODES/256)

typedef __attribute__((ext_vector_type(8))) short  short8;
typedef __attribute__((ext_vector_type(4))) float  f32x4;

__device__ __forceinline__ ushort f2b(float f) {
    __hip_bfloat16 b = __float2bfloat16(f);
    return *reinterpret_cast<ushort*>(&b);
}
__device__ __forceinline__ float b2f(ushort u) { return __uint_as_float(((uint)u) << 16); }
__device__ __forceinline__ float sigm(float x)  { return 1.f / (1.f + __expf(-x)); }
__device__ __forceinline__ float tanhx(float x) { float e = __expf(2.f * x); return 1.f - 2.f / (e + 1.f); }
// fragment-slot swizzle: spreads simultaneous epilogue writes across bank slots
__device__ __forceinline__ int SW(int fl) { return fl ^ (fl >> 3); }

// ---------------------------------------------------------------- CSR build
__global__ void k_deg(const int* __restrict__ ei, int* __restrict__ deg) {
    int e = blockIdx.x * 256 + threadIdx.x;
    if (e < E_EDGES) atomicAdd(&deg[ei[E_EDGES + e]], 1);
}

__global__ __launch_bounds__(256)
void k_scan1(const int* __restrict__ deg, int* __restrict__ incl, int* __restrict__ bsum) {
    __shared__ int sA[256], sB[256];
    int tid = threadIdx.x;
    int i = blockIdx.x * 256 + tid;
    sA[tid] = (i < N_NODES) ? deg[i] : 0;
    __syncthreads();
    int* rd = sA; int* wr = sB;
    for (int off = 1; off < 256; off <<= 1) {
        int v = rd[tid];
        if (tid >= off) v += rd[tid - off];
        wr[tid] = v;
        __syncthreads();
        int* tmp = rd; rd = wr; wr = tmp;
    }
    incl[i] = rd[tid];
    if (tid == 255) bsum[blockIdx.x] = rd[255];
}

__global__ void k_scan2(const int* __restrict__ bsum, int* __restrict__ boff,
                        int* __restrict__ row_ptr) {
    __shared__ int sA[256], sB[256];
    int tid = threadIdx.x;
    int v0 = (tid < NBLK) ? bsum[tid] : 0;
    sA[tid] = v0;
    __syncthreads();
    int* rd = sA; int* wr = sB;
    for (int off = 1; off < 256; off <<= 1) {
        int v = rd[tid];
        if (tid >= off) v += rd[tid - off];
        wr[tid] = v;
        __syncthreads();
        int* tmp = rd; rd = wr; wr = tmp;
    }
    if (tid < NBLK) boff[tid] = rd[tid] - v0;
    if (tid == NBLK - 1) row_ptr[N_NODES] = rd[tid];
}

__global__ __launch_bounds__(256)
void k_scan3(const int* __restrict__ deg, const int* __restrict__ incl,
             const int* __restrict__ boff, int* __restrict__ row_ptr,
             int* __restrict__ cursor, float* __restrict__ rdeg) {
    int i = blockIdx.x * 256 + threadIdx.x;
    if (i >= N_NODES) return;
    int d = deg[i];
    int excl = incl[i] - d + boff[blockIdx.x];
    row_ptr[i] = excl;
    cursor[i]  = excl;
    rdeg[i] = 1.0f / (float)max(d, 1);
}

__global__ void k_bucket(const int* __restrict__ ei, int* __restrict__ cursor,
                         int* __restrict__ csr_src) {
    int e = blockIdx.x * 256 + threadIdx.x;
    if (e < E_EDGES) {
        int d = ei[E_EDGES + e];
        int slot = atomicAdd(&cursor[d], 1);
        csr_src[slot] = ei[e];
    }
}

// ---------------------------------------------------------------- x -> bf16
__global__ __launch_bounds__(256)
void k_xbf(const float* __restrict__ x, ushort* __restrict__ xb) {
    size_t i = ((size_t)blockIdx.x * 256 + threadIdx.x) * 4;
    float4 v = *(const float4*)(x + i);
    ushort4 o; o.x = f2b(v.x); o.y = f2b(v.y); o.z = f2b(v.z); o.w = f2b(v.w);
    *(ushort4*)(xb + i) = o;
}

// ------------------------------------------------- fragment-order B packing
// Bf: rz [16 ct][8 ks][64][8] (cols 0-127 r, 128-255 z, K=256)
//     n1 @65536: [8 ct][4 ks][64][8] (n cols, sp half K=128, W_ih rows 256..383)
//     n2 @81920: [8 ct][4 ks][64][8] (n cols, h  half K=128, W_hh rows 256..383)
// Bsf: [8 ct][2 ks][64][8];  B2f: [6 ct][4 ks][64][8]
__global__ void k_pack(const float* __restrict__ Wih, const float* __restrict__ Whh,
                       const float* __restrict__ Wl,  const float* __restrict__ Wr,
                       const float* __restrict__ Wrec,const float* __restrict__ Wc1,
                       short* __restrict__ Bf, short* __restrict__ Bsf, short* __restrict__ B2f) {
    int i = blockIdx.x * 256 + threadIdx.x;
    if (i < 65536) {                                   // rz
        int b = i & 7, lane = (i >> 3) & 63, ks = (i >> 9) & 7, ct = i >> 12;
        int col = ct * 16 + (lane & 15);               // 0..255
        int k = ks * 32 + ((lane >> 4) << 3) + b;      // 0..255
        float v = (k < 128) ? Wih[col * 128 + k] : Whh[col * 128 + (k - 128)];
        Bf[i] = (short)f2b(v);
    } else if (i < 81920) {                            // n1
        int t2 = i - 65536;
        int b = t2 & 7, lane = (t2 >> 3) & 63, ks = (t2 >> 9) & 3, ct = t2 >> 11;
        int col = 256 + ct * 16 + (lane & 15);         // W_ih rows 256..383
        int k = ks * 32 + ((lane >> 4) << 3) + b;      // 0..127
        Bf[i] = (short)f2b(Wih[col * 128 + k]);
    } else if (i < 98304) {                            // n2
        int t2 = i - 81920;
        int b = t2 & 7, lane = (t2 >> 3) & 63, ks = (t2 >> 9) & 3, ct = t2 >> 11;
        int col = 256 + ct * 16 + (lane & 15);         // W_hh rows 256..383
        int k = ks * 32 + ((lane >> 4) << 3) + b;
        Bf[i] = (short)f2b(Whh[col * 128 + k]);
    } else if (i < 106496) {                           // Bsf
        int t2 = i - 98304;
        int b = t2 & 7, lane = (t2 >> 3) & 63, ks = (t2 >> 9) & 1, ct = t2 >> 10;
        int col = ct * 16 + (lane & 15);
        int k = ks * 32 + ((lane >> 4) << 3) + b;
        float v = (k < 32) ? Wl[col * 32 + k] : Wr[col * 32 + (k - 32)];
        Bsf[t2] = (short)f2b(v);
    } else if (i < 118784) {                           // B2f
        int t3 = i - 106496;
        int b = t3 & 7, lane = (t3 >> 3) & 63, ks = (t3 >> 9) & 3, ct = t3 >> 11;
        int col = ct * 16 + (lane & 15);
        int k = ks * 32 + ((lane >> 4) << 3) + b;
        float v = (col < 32) ? Wrec[col * 128 + k] : Wc1[(col - 32) * 128 + k];
        B2f[t3] = (short)f2b(v);
    }
}

// ---------------- mean aggregation over bf16 x, all timesteps, f32 accum
__global__ __launch_bounds__(256)
void k_agg_all(const ushort* __restrict__ xb, const int* __restrict__ row_ptr,
               const int* __restrict__ csr_src, const float* __restrict__ rdeg,
               ushort* __restrict__ aggb) {
    int g = blockIdx.x * 256 + threadIdx.x;
    int node = g >> 3, st = (g & 7) * 4;
    if (node >= N_NODES) return;
    int e0 = row_ptr[node], e1 = row_ptr[node + 1];
    float acc[8][4];
#pragma unroll
    for (int t = 0; t < 8; ++t)
#pragma unroll
        for (int c = 0; c < 4; ++c) acc[t][c] = 0.f;
    for (int e = e0; e < e1; ++e) {
        int s = csr_src[e];
        const ushort* b = xb + (size_t)s * (T_STEPS * CIN) + st;
#pragma unroll
        for (int t = 0; t < 8; ++t) {
            ushort4 v = *(const ushort4*)(b + t * CIN);
            acc[t][0] += b2f(v.x); acc[t][1] += b2f(v.y);
            acc[t][2] += b2f(v.z); acc[t][3] += b2f(v.w);
        }
    }
    float r = rdeg[node];
    ushort* o = aggb + (size_t)node * (T_STEPS * CIN) + st;
#pragma unroll
    for (int t = 0; t < 8; ++t) {
        ushort4 v; v.x = f2b(acc[t][0] * r); v.y = f2b(acc[t][1] * r);
        v.z = f2b(acc[t][2] * r); v.w = f2b(acc[t][3] * r);
        *(ushort4*)(o + t * CIN) = v;
    }
}

// GRU row-half: rows RH*32..RH*32+31 (acc regs halved -> no spill; R6 had
// ~85MB/dispatch scratch traffic from 64 live acc VGPRs at the 128 cap).
template<int RH>
__device__ __forceinline__ void gru_half(const short* lds, const short* __restrict__ Bf,
                                         int wv, int lane, float br_, float bz_,
                                         float bihn, float bhhn, float (&hold)[4][4]) {
    f32x4 accR[2], accZ[2], accN1[2], accN2[2];
#pragma unroll
    for (int ri = 0; ri < 2; ++ri) {
        accR[ri]  = (f32x4){0.f, 0.f, 0.f, 0.f};
        accZ[ri]  = (f32x4){0.f, 0.f, 0.f, 0.f};
        accN1[ri] = (f32x4){0.f, 0.f, 0.f, 0.f};
        accN2[ri] = (f32x4){0.f, 0.f, 0.f, 0.f};
    }
#pragma unroll
    for (int ks = 0; ks < 4; ++ks) {               // sp half (k<128)
        short8 av[2];
#pragma unroll
        for (int ri = 0; ri < 2; ++ri)
            av[ri] = *(const short8*)&lds[((ks * 4 + RH * 2 + ri) * 64 + SW(lane)) * 8];
        short8 b0 = *(const short8*)(Bf + (((0 * 8 + wv) * 8 + ks) * 64 + lane) * 8);
        short8 b1 = *(const short8*)(Bf + (((1 * 8 + wv) * 8 + ks) * 64 + lane) * 8);
        short8 bn = *(const short8*)(Bf + (65536 + ((wv * 4 + ks) * 64 + lane) * 8));
#pragma unroll
        for (int ri = 0; ri < 2; ++ri) {
            accR[ri]  = __builtin_amdgcn_mfma_f32_16x16x32_bf16(av[ri], b0, accR[ri], 0, 0, 0);
            accZ[ri]  = __builtin_amdgcn_mfma_f32_16x16x32_bf16(av[ri], b1, accZ[ri], 0, 0, 0);
            accN1[ri] = __builtin_amdgcn_mfma_f32_16x16x32_bf16(av[ri], bn, accN1[ri], 0, 0, 0);
        }
    }
#pragma unroll
    for (int ks = 4; ks < 8; ++ks) {               // h half (k>=128)
        short8 av[2];
#pragma unroll
        for (int ri = 0; ri < 2; ++ri)
            av[ri] = *(const short8*)&lds[((ks * 4 + RH * 2 + ri) * 64 + SW(lane)) * 8];
        short8 b0 = *(const short8*)(Bf + (((0 * 8 + wv) * 8 + ks) * 64 + lane) * 8);
        short8 b1 = *(const short8*)(Bf + (((1 * 8 + wv) * 8 + ks) * 64 + lane) * 8);
        short8 bn = *(const short8*)(Bf + (81920 + ((wv * 4 + (ks - 4)) * 64 + lane) * 8));
#pragma unroll
        for (int ri = 0; ri < 2; ++ri) {
            accR[ri]  = __builtin_amdgcn_mfma_f32_16x16x32_bf16(av[ri], b0, accR[ri], 0, 0, 0);
            accZ[ri]  = __builtin_amdgcn_mfma_f32_16x16x32_bf16(av[ri], b1, accZ[ri], 0, 0, 0);
            accN2[ri] = __builtin_amdgcn_mfma_f32_16x16x32_bf16(av[ri], bn, accN2[ri], 0, 0, 0);
        }
    }
    // gates for this row half (h fp32 in registers across steps)
#pragma unroll
    for (int ri = 0; ri < 2; ++ri)
#pragma unroll
        for (int q = 0; q < 4; ++q) {
            float r = sigm(accR[ri][q] + br_);
            float z = sigm(accZ[ri][q] + bz_);
            float nn = tanhx(accN1[ri][q] + bihn + r * (accN2[ri][q] + bhhn));
            hold[RH * 2 + ri][q] = (1.f - z) * nn + z * hold[RH * 2 + ri][q];
        }
}

// --------- ALL 8 timesteps fused: SAGE + GRU + heads, 3 barriers/step
// block: 64 nodes x 512 threads (8 waves). wave wv owns 16-col slice j=wv*16+li.
// LDS shorts: A [8ks][4ri][64 slot][8] (32KB: ks0-3 sp, ks4-7 h);
//             A_s @16384 (8KB); c1f (f32) @20480 shorts (16KB). Total 56KB.
// Heads for step t computed in P1 of step t+1 (h(t) still staged); cls one later.
// NOTE: (512,2) not (512,4) — LDS caps at 2 blocks/CU; tighter bound spills
// (R5: 387MB WRITE_SIZE). GRU in two row-halves to fit 128 VGPR (R6: 140MB).
__global__ __launch_bounds__(512, 2)
void k_rec(const ushort* __restrict__ aggb, const ushort* __restrict__ xb,
           const short* __restrict__ Bsf, const short* __restrict__ Bf,
           const short* __restrict__ B2f,
           const float* __restrict__ bl,
           const float* __restrict__ b_ih, const float* __restrict__ b_hh,
           const float* __restrict__ b_rec, const float* __restrict__ b_c1,
           const float* __restrict__ W_c2, const float* __restrict__ b_c2,
           float* __restrict__ out_rec, float* __restrict__ out_cls) {
    __shared__ short lds[28672];
    float* c1f = (float*)&lds[20480];
    const int tid = threadIdx.x;
    const int nb  = blockIdx.x * 64;
    const int wv   = __builtin_amdgcn_readfirstlane(tid >> 6);
    const int lane = tid & 63;
    const int li   = lane & 15, lq = lane >> 4;
    const int j    = wv * 16 + li;

    // zero h region (A ks4..7)
    for (int c = tid; c < 1024; c += 512)
        *(short8*)&lds[8192 + c * 8] = (short8){0, 0, 0, 0, 0, 0, 0, 0};

    float hold[4][4];
#pragma unroll
    for (int ri = 0; ri < 4; ++ri)
#pragma unroll
        for (int q = 0; q < 4; ++q) hold[ri][q] = 0.f;

    // hoisted per-lane biases
    const float blc  = bl[j];
    const float br_  = b_ih[j]       + b_hh[j];
    const float bz_  = b_ih[128 + j] + b_hh[128 + j];
    const float bihn = b_ih[256 + j], bhhn = b_hh[256 + j];
    float bhead = 0.f;
    if (wv < 2)      bhead = b_rec[j];
    else if (wv < 6) bhead = b_c1[j - 32];

    // staging geometry + prefetch (t=0 in prologue)
    const int snode = tid >> 3, sk0 = (tid & 7) * 8;
    const int sgn = nb + snode;
    const ushort* sp0 = nullptr;
    if (sgn < N_NODES)
        sp0 = ((sk0 < 32) ? aggb : xb) + (size_t)sgn * (T_STEPS * CIN) + (sk0 & 31);
    const int sdst = 16384 + (((sk0 >> 5) * 4 + (snode >> 4)) * 64
                              + SW(((sk0 & 31) >> 3) * 16 + (snode & 15))) * 8;
    short8 pv = (short8){0, 0, 0, 0, 0, 0, 0, 0};
    if (sp0) pv = *(const short8*)(sp0);

    // heads GEMM on h currently staged in A ks4..7; writes out_rec(tt) / c1f
    auto do_heads = [&](int tt) {
        f32x4 accH[4];
#pragma unroll
        for (int ri = 0; ri < 4; ++ri) accH[ri] = (f32x4){0.f, 0.f, 0.f, 0.f};
#pragma unroll
        for (int ksh = 0; ksh < 4; ++ksh) {
            short8 a[4];
#pragma unroll
            for (int ri = 0; ri < 4; ++ri)
                a[ri] = *(short8*)&lds[(((4 + ksh) * 4 + ri) * 64 + SW(lane)) * 8];
            short8 b = *(const short8*)(B2f + ((wv * 4 + ksh) * 64 + lane) * 8);
#pragma unroll
            for (int ri = 0; ri < 4; ++ri)
                accH[ri] = __builtin_amdgcn_mfma_f32_16x16x32_bf16(a[ri], b, accH[ri], 0, 0, 0);
        }
        if (wv < 2) {
#pragma unroll
            for (int ri = 0; ri < 4; ++ri)
#pragma unroll
                for (int q = 0; q < 4; ++q) {
                    int row = ri * 16 + lq * 4 + q, gn = nb + row;
                    if (gn < N_NODES)
                        out_rec[(size_t)gn * (T_STEPS * 32) + tt * 32 + j] = accH[ri][q] + bhead;
                }
        } else {
            int cc = j - 32;
#pragma unroll
            for (int ri = 0; ri < 4; ++ri)
#pragma unroll
                for (int q = 0; q < 4; ++q) {
                    int row = ri * 16 + lq * 4 + q;
                    c1f[row * 64 + (cc ^ (row & 31))] = fmaxf(accH[ri][q] + bhead, 0.f);
                }
        }
    };
    auto do_cls = [&](int tt) {
        int node = tid >> 3, st = tid & 7, gn2 = nb + node;
        float s = 0.f;
#pragma unroll
        for (int c = 0; c < 8; ++c) {
            int q = st * 8 + c;
            s = fmaf(W_c2[q], c1f[node * 64 + (q ^ (node & 31))], s);
        }
        s += __shfl_xor(s, 1);
        s += __shfl_xor(s, 2);
        s += __shfl_xor(s, 4);
        if (st == 0 && gn2 < N_NODES)
            out_cls[(size_t)gn2 * T_STEPS + tt] = sigm(s + b_c2[0]);
    };

    for (int t = 0; t < T_STEPS; ++t) {
        // ---- stage A_s (prefetched regs) ----
        *(short8*)&lds[sdst] = pv;
        __syncthreads();                               // B1: A_s + h(t-1) ready
        if (sp0 && t + 1 < T_STEPS) pv = *(const short8*)(sp0 + (t + 1) * CIN);

        // ---- P1: SAGE(t) MFMA + heads(t-1) MFMA (disjoint LDS reads) ----
        {
            f32x4 accS[4];
#pragma unroll
            for (int ri = 0; ri < 4; ++ri) accS[ri] = (f32x4){0.f, 0.f, 0.f, 0.f};
#pragma unroll
            for (int ks = 0; ks < 2; ++ks) {
                short8 a[4];
#pragma unroll
                for (int ri = 0; ri < 4; ++ri)
                    a[ri] = *(short8*)&lds[16384 + ((ks * 4 + ri) * 64 + SW(lane)) * 8];
                short8 b = *(const short8*)(Bsf + ((wv * 2 + ks) * 64 + lane) * 8);
#pragma unroll
                for (int ri = 0; ri < 4; ++ri)
                    accS[ri] = __builtin_amdgcn_mfma_f32_16x16x32_bf16(a[ri], b, accS[ri], 0, 0, 0);
            }
            if (t > 0 && wv < 6) do_heads(t - 1);
            // write sp -> A ks0..3
            int ks_t = j >> 5, lh = (j & 31) >> 3, jj = j & 7;
#pragma unroll
            for (int ri = 0; ri < 4; ++ri)
#pragma unroll
                for (int q = 0; q < 4; ++q) {
                    float v = fmaxf(accS[ri][q] + blc, 0.f);
                    lds[((ks_t * 4 + ri) * 64 + SW(lh * 16 + lq * 4 + q)) * 8 + jj] = (short)f2b(v);
                }
        }
        __syncthreads();                               // B2: sp + c1f ready

        // ---- P2: GRU in two row-halves (VGPR-capped, no spill) ----
        gru_half<0>(lds, Bf, wv, lane, br_, bz_, bihn, bhhn, hold);
        __builtin_amdgcn_sched_barrier(0);             // keep halves' live ranges apart
        gru_half<1>(lds, Bf, wv, lane, br_, bz_, bihn, bhhn, hold);

        if (t > 0) do_cls(t - 1);
        __syncthreads();                               // B3: all A-reads done

        // ---- h(t) -> A ks4..7 ----
        {
            int ks_h = 4 + (j >> 5), lh_h = (j & 31) >> 3, jj_h = j & 7;
#pragma unroll
            for (int ri = 0; ri < 4; ++ri)
#pragma unroll
                for (int q = 0; q < 4; ++q)
                    lds[((ks_h * 4 + ri) * 64 + SW(lh_h * 16 + lq * 4 + q)) * 8 + jj_h]
                        = (short)f2b(hold[ri][q]);
        }
    }

    // ---- epilogue: heads + cls for t = 7 ----
    __syncthreads();
    if (wv < 6) do_heads(T_STEPS - 1);
    __syncthreads();
    do_cls(T_STEPS - 1);
}

// ---------------------------------------------------------------- launcher
extern "C" void kernel_launch(void* const* d_in, const int* in_sizes, int n_in,
                              void* d_out, int out_size, void* d_ws, size_t ws_size,
                              hipStream_t stream) {
    const float* x     = (const float*)d_in[0];
    const int*   ei    = (const int*)  d_in[1];
    const float* Wl    = (const float*)d_in[2];
    const float* bl    = (const float*)d_in[3];
    const float* Wr    = (const float*)d_in[4];
    const float* W_ih  = (const float*)d_in[5];
    const float* b_ih  = (const float*)d_in[6];
    const float* W_hh  = (const float*)d_in[7];
    const float* b_hh  = (const float*)d_in[8];
    const float* W_rec = (const float*)d_in[9];
    const float* b_rec = (const float*)d_in[10];
    const float* W_c1  = (const float*)d_in[11];
    const float* b_c1  = (const float*)d_in[12];
    const float* W_c2  = (const float*)d_in[13];
    const float* b_c2  = (const float*)d_in[14];

    char* wp = (char*)d_ws;
    auto alloc = [&](size_t bytes) -> char* {
        char* p = wp; wp += (bytes + 255) & ~(size_t)255; return p;
    };
    int*    deg     = (int*)   alloc((size_t)N_NODES * 4);
    int*    row_ptr = (int*)   alloc((size_t)(N_NODES + 1) * 4);
    int*    cursor  = (int*)   alloc((size_t)N_NODES * 4);
    int*    csr_src = (int*)   alloc((size_t)E_EDGES * 4);
    float*  rdeg    = (float*) alloc((size_t)N_NODES * 4);
    int*    incl    = (int*)   alloc((size_t)NBLK * 256 * 4);
    int*    bsum    = (int*)   alloc((size_t)256 * 4);
    int*    boff    = (int*)   alloc((size_t)256 * 4);
    short*  Bf      = (short*) alloc((size_t)98304 * 2);
    short*  Bsf     = (short*) alloc((size_t)8192 * 2);
    short*  B2f     = (short*) alloc((size_t)12288 * 2);
    ushort* xb      = (ushort*)alloc((size_t)N_NODES * T_STEPS * CIN * 2);
    ushort* aggb    = (ushort*)alloc((size_t)N_NODES * T_STEPS * CIN * 2);

    float* out_rec = (float*)d_out;
    float* out_cls = out_rec + (size_t)N_NODES * T_STEPS * 32;

    hipMemsetAsync(deg, 0, (size_t)N_NODES * 4, stream);

    k_deg   <<<(E_EDGES + 255) / 256, 256, 0, stream>>>(ei, deg);
    k_scan1 <<<NBLK, 256, 0, stream>>>(deg, incl, bsum);
    k_scan2 <<<1, 256, 0, stream>>>(bsum, boff, row_ptr);
    k_scan3 <<<NBLK, 256, 0, stream>>>(deg, incl, boff, row_ptr, cursor, rdeg);
    k_bucket<<<(E_EDGES + 255) / 256, 256, 0, stream>>>(ei, cursor, csr_src);
    k_xbf   <<<12500, 256, 0, stream>>>(x, xb);
    k_pack  <<<464, 256, 0, stream>>>(W_ih, W_hh, Wl, Wr, W_rec, W_c1, Bf, Bsf, B2f);

    k_agg_all<<<(N_NODES * 8 + 255) / 256, 256, 0, stream>>>(
        xb, row_ptr, csr_src, rdeg, aggb);
    k_rec<<<(N_NODES + 63) / 64, 512, 0, stream>>>(
        aggb, xb, Bsf, Bf, B2f, bl, b_ih, b_hh, b_rec, b_c1, W_c2, b_c2,
        out_rec, out_cls);
}